// Round 2
// baseline (4038.668 us; speedup 1.0000x reference)
//
#include <hip/hip_runtime.h>
#include <hip/hip_bf16.h>

// AKT forward, f32 baseline (round 2).
//   - glo term dropped (additive per-query constant, softmax-invariant)
//   - pos_key folded into k in the k-GEMM epilogue (q·k^T + q·pe^T = q·(k+pe)^T)
//   - output written as FLOAT32 (reference output dtype)
//   - workspace: 4 x [4096,1024] f32 buffers = 67.1 MB (liveness-aliased)
//
// Buffer liveness per layer:
//   q0:   X  -> Qb
//   k:    Qb -> Kb   (+pe fold)
//   v:    Qb -> Vb
//   attn: Qb,Kb,Vb -> X      (X dead since q0)
//   mlp1: X  -> Qb           (Qb dead after attn)
//   mlp2: Qb -> Kb           (Kb dead after attn)
//   mlp3: Kb -> X            (X dead after mlp1)

#define B_ 4
#define S_ 1024
#define E_ 1024
#define H_ 16
#define D_ 64
#define L_ 4
#define M_ (B_ * S_)  // 4096

__device__ __forceinline__ float gelu_exact(float x) {
    return 0.5f * x * (1.0f + erff(x * 0.70710678118654752f));
}

// ---------------------------------------------------------------------------
// C[M_,1024] = A[M_,K] * Bm[1024,K]^T + bias ; optional GELU, optional pe-add
// 64x64 tile, BK=16, 256 threads, 4x4 micro-tile per thread.
// ---------------------------------------------------------------------------
template <int ACT, int ADD_PE>
__global__ __launch_bounds__(256) void gemm_nt(
    const float* __restrict__ A, const float* __restrict__ Bm,
    const float* __restrict__ bias, float* __restrict__ C, int K,
    const float* __restrict__ pe) {
    __shared__ float As[16][68];
    __shared__ float Bs[16][68];
    const int tid = threadIdx.x;
    const int ty = tid >> 4, tx = tid & 15;
    const int m0 = blockIdx.y * 64, n0 = blockIdx.x * 64;
    const int lrow = tid >> 2;
    const int lk = (tid & 3) << 2;
    float acc[4][4] = {};
    const float* Aptr = A + (size_t)(m0 + lrow) * K + lk;
    const float* Bptr = Bm + (size_t)(n0 + lrow) * K + lk;
    for (int k0 = 0; k0 < K; k0 += 16) {
        const float4 av = *(const float4*)(Aptr + k0);
        const float4 bv = *(const float4*)(Bptr + k0);
        __syncthreads();
        As[lk + 0][lrow] = av.x; As[lk + 1][lrow] = av.y;
        As[lk + 2][lrow] = av.z; As[lk + 3][lrow] = av.w;
        Bs[lk + 0][lrow] = bv.x; Bs[lk + 1][lrow] = bv.y;
        Bs[lk + 2][lrow] = bv.z; Bs[lk + 3][lrow] = bv.w;
        __syncthreads();
#pragma unroll
        for (int kk = 0; kk < 16; ++kk) {
            const float4 a = *(const float4*)&As[kk][ty << 2];
            const float4 b = *(const float4*)&Bs[kk][tx << 2];
            const float a4[4] = {a.x, a.y, a.z, a.w};
            const float b4[4] = {b.x, b.y, b.z, b.w};
#pragma unroll
            for (int i = 0; i < 4; ++i)
#pragma unroll
                for (int j = 0; j < 4; ++j)
                    acc[i][j] = fmaf(a4[i], b4[j], acc[i][j]);
        }
    }
#pragma unroll
    for (int i = 0; i < 4; ++i) {
        const int m = m0 + (ty << 2) + i;
#pragma unroll
        for (int j = 0; j < 4; ++j) {
            const int n = n0 + (tx << 2) + j;
            float v = acc[i][j] + bias[n];
            if (ADD_PE) v += pe[((m & (S_ - 1)) << 6) + (n & (D_ - 1))];
            if (ACT) v = gelu_exact(v);
            C[(size_t)m * E_ + n] = v;
        }
    }
}

// ---------------------------------------------------------------------------
// x = concat(emb_item[item_idx], emb_skill[skill_idx]) @ W_in^T + b_in
// ---------------------------------------------------------------------------
__global__ __launch_bounds__(256) void embed_gemm(
    const int* __restrict__ item_idx, const int* __restrict__ skill_idx,
    const float* __restrict__ emb_item, const float* __restrict__ emb_skill,
    const float* __restrict__ Bm, const float* __restrict__ bias,
    float* __restrict__ C) {
    const int K = 2 * E_;
    __shared__ float As[16][68];
    __shared__ float Bs[16][68];
    const int tid = threadIdx.x;
    const int ty = tid >> 4, tx = tid & 15;
    const int m0 = blockIdx.y * 64, n0 = blockIdx.x * 64;
    const int lrow = tid >> 2;
    const int lk = (tid & 3) << 2;
    const int row = m0 + lrow;
    const int ii = item_idx[row];
    const int si = skill_idx[row];
    const float* itemrow = emb_item + (size_t)ii * E_;
    const float* skillrow = emb_skill + (size_t)si * E_;
    const float* Bptr = Bm + (size_t)(n0 + lrow) * K + lk;
    float acc[4][4] = {};
    for (int k0 = 0; k0 < K; k0 += 16) {
        const int k = k0 + lk;
        const float4 av = (k < E_) ? *(const float4*)(itemrow + k)
                                   : *(const float4*)(skillrow + (k - E_));
        const float4 bv = *(const float4*)(Bptr + k0);
        __syncthreads();
        As[lk + 0][lrow] = av.x; As[lk + 1][lrow] = av.y;
        As[lk + 2][lrow] = av.z; As[lk + 3][lrow] = av.w;
        Bs[lk + 0][lrow] = bv.x; Bs[lk + 1][lrow] = bv.y;
        Bs[lk + 2][lrow] = bv.z; Bs[lk + 3][lrow] = bv.w;
        __syncthreads();
#pragma unroll
        for (int kk = 0; kk < 16; ++kk) {
            const float4 a = *(const float4*)&As[kk][ty << 2];
            const float4 b = *(const float4*)&Bs[kk][tx << 2];
            const float a4[4] = {a.x, a.y, a.z, a.w};
            const float b4[4] = {b.x, b.y, b.z, b.w};
#pragma unroll
            for (int i = 0; i < 4; ++i)
#pragma unroll
                for (int j = 0; j < 4; ++j)
                    acc[i][j] = fmaf(a4[i], b4[j], acc[i][j]);
        }
    }
#pragma unroll
    for (int i = 0; i < 4; ++i) {
        const int m = m0 + (ty << 2) + i;
#pragma unroll
        for (int j = 0; j < 4; ++j) {
            const int n = n0 + (tx << 2) + j;
            C[(size_t)m * E_ + n] = acc[i][j] + bias[n];
        }
    }
}

// ---------------------------------------------------------------------------
// Flash-style attention per (b,h): O = softmax(Q Keff^T / 8) V
// Q tile = 32 queries, KV tile = 64 keys, 256 threads.
// ---------------------------------------------------------------------------
__global__ __launch_bounds__(256) void attn_kernel(
    const float* __restrict__ Q, const float* __restrict__ Kf,
    const float* __restrict__ V, float* __restrict__ O) {
    __shared__ float Qt[64][36];  // [d][q]
    __shared__ float Kt[64][68];  // [d][k]
    __shared__ float Vs[64][68];  // [k][d]
    __shared__ float Ps[32][68];  // [q][k]
    const int tid = threadIdx.x;
    const int ty = tid >> 4, tx = tid & 15;
    const int qpos = blockIdx.x * 32;
    const int bb = blockIdx.y >> 4;
    const int hh = blockIdx.y & 15;
    const size_t headoff = (size_t)hh * D_;

    // stage Q transposed: Qt[d][q]
    {
        const int r = tid >> 3;      // 0..31
        const int c = tid & 7;       // 0..7 -> chunks c, c+8
        const float* qrow = Q + ((size_t)(bb * S_ + qpos + r)) * E_ + headoff;
        const float4 q1 = *(const float4*)(qrow + (c << 2));
        const float4 q2 = *(const float4*)(qrow + ((c + 8) << 2));
        Qt[(c << 2) + 0][r] = q1.x; Qt[(c << 2) + 1][r] = q1.y;
        Qt[(c << 2) + 2][r] = q1.z; Qt[(c << 2) + 3][r] = q1.w;
        Qt[(c << 2) + 32][r] = q2.x; Qt[(c << 2) + 33][r] = q2.y;
        Qt[(c << 2) + 34][r] = q2.z; Qt[(c << 2) + 35][r] = q2.w;
    }

    float m_i[2] = {-INFINITY, -INFINITY};
    float l_i[2] = {0.f, 0.f};
    float o[2][4] = {};

    const int kr = tid >> 2;   // 0..63  (staging row)
    const int c0 = tid & 3;    // chunk start

    for (int kt = 0; kt < S_ / 64; ++kt) {
        __syncthreads();
        // stage K (transposed) and V
        {
            const float* krow = Kf + ((size_t)(bb * S_ + kt * 64 + kr)) * E_ + headoff;
            const float* vrow = V + ((size_t)(bb * S_ + kt * 64 + kr)) * E_ + headoff;
#pragma unroll
            for (int cc = c0; cc < 16; cc += 4) {
                const float4 kv = *(const float4*)(krow + (cc << 2));
                Kt[(cc << 2) + 0][kr] = kv.x; Kt[(cc << 2) + 1][kr] = kv.y;
                Kt[(cc << 2) + 2][kr] = kv.z; Kt[(cc << 2) + 3][kr] = kv.w;
                *(float4*)&Vs[kr][cc << 2] = *(const float4*)(vrow + (cc << 2));
            }
        }
        __syncthreads();
        // scores 2x4 per thread
        float sc[2][4] = {};
#pragma unroll 8
        for (int d = 0; d < 64; ++d) {
            const float2 aq = *(const float2*)&Qt[d][ty << 1];
            const float4 bk = *(const float4*)&Kt[d][tx << 2];
            const float b4[4] = {bk.x, bk.y, bk.z, bk.w};
#pragma unroll
            for (int j = 0; j < 4; ++j) {
                sc[0][j] = fmaf(aq.x, b4[j], sc[0][j]);
                sc[1][j] = fmaf(aq.y, b4[j], sc[1][j]);
            }
        }
#pragma unroll
        for (int i = 0; i < 2; ++i) {
#pragma unroll
            for (int j = 0; j < 4; ++j) sc[i][j] *= 0.125f;
            float rmax = fmaxf(fmaxf(sc[i][0], sc[i][1]), fmaxf(sc[i][2], sc[i][3]));
#pragma unroll
            for (int off = 1; off < 16; off <<= 1)
                rmax = fmaxf(rmax, __shfl_xor(rmax, off, 16));
            const float mnew = fmaxf(m_i[i], rmax);
            const float corr = __expf(m_i[i] - mnew);
            float p[4], rsum = 0.f;
#pragma unroll
            for (int j = 0; j < 4; ++j) {
                p[j] = __expf(sc[i][j] - mnew);
                rsum += p[j];
            }
#pragma unroll
            for (int off = 1; off < 16; off <<= 1)
                rsum += __shfl_xor(rsum, off, 16);
            l_i[i] = l_i[i] * corr + rsum;
            m_i[i] = mnew;
#pragma unroll
            for (int j = 0; j < 4; ++j) o[i][j] *= corr;
            Ps[(ty << 1) + i][(tx << 2) + 0] = p[0];
            Ps[(ty << 1) + i][(tx << 2) + 1] = p[1];
            Ps[(ty << 1) + i][(tx << 2) + 2] = p[2];
            Ps[(ty << 1) + i][(tx << 2) + 3] = p[3];
        }
        __syncthreads();
        // PV: o[i][dj] += sum_j Ps[q][j] * Vs[j][d]
#pragma unroll 8
        for (int j = 0; j < 64; ++j) {
            const float pr0 = Ps[(ty << 1) + 0][j];
            const float pr1 = Ps[(ty << 1) + 1][j];
            const float4 vv = *(const float4*)&Vs[j][tx << 2];
            const float v4[4] = {vv.x, vv.y, vv.z, vv.w};
#pragma unroll
            for (int dj = 0; dj < 4; ++dj) {
                o[0][dj] = fmaf(pr0, v4[dj], o[0][dj]);
                o[1][dj] = fmaf(pr1, v4[dj], o[1][dj]);
            }
        }
    }
#pragma unroll
    for (int i = 0; i < 2; ++i) {
        const float inv_l = 1.f / l_i[i];
        float4 ov;
        ov.x = o[i][0] * inv_l; ov.y = o[i][1] * inv_l;
        ov.z = o[i][2] * inv_l; ov.w = o[i][3] * inv_l;
        float* orow = O + ((size_t)(bb * S_ + qpos + (ty << 1) + i)) * E_ + headoff + (tx << 2);
        *(float4*)orow = ov;
    }
}

// ---------------------------------------------------------------------------
// out[m] = x[m,:] . W_out + b_out, FLOAT32 output. One wave per row.
// ---------------------------------------------------------------------------
__global__ __launch_bounds__(256) void final_proj(
    const float* __restrict__ X, const float* __restrict__ Wout,
    const float* __restrict__ bout, float* __restrict__ out) {
    const int wid = threadIdx.x >> 6, lane = threadIdx.x & 63;
    const int m = blockIdx.x * 4 + wid;
    const float* xrow = X + (size_t)m * E_;
    float acc = 0.f;
#pragma unroll
    for (int c = 0; c < 4; ++c) {
        const int f4 = c * 64 + lane;
        const float4 xv = *(const float4*)(xrow + (f4 << 2));
        const float4 wv = *(const float4*)(Wout + (f4 << 2));
        acc += xv.x * wv.x + xv.y * wv.y + xv.z * wv.z + xv.w * wv.w;
    }
#pragma unroll
    for (int off = 32; off; off >>= 1) acc += __shfl_xor(acc, off, 64);
    if (lane == 0) out[m] = acc + bout[0];
}

extern "C" void kernel_launch(void* const* d_in, const int* in_sizes, int n_in,
                              void* d_out, int out_size, void* d_ws, size_t ws_size,
                              hipStream_t stream) {
    const int* item_inputs = (const int*)d_in[0];
    const int* skill_inputs = (const int*)d_in[1];
    const float* emb_item = (const float*)d_in[5];
    const float* emb_skill = (const float*)d_in[6];
    const float* W_in = (const float*)d_in[7];
    const float* b_in = (const float*)d_in[8];
    const float* Wq = (const float*)d_in[9];
    const float* bq = (const float*)d_in[10];
    const float* Wk = (const float*)d_in[11];
    const float* bk = (const float*)d_in[12];
    const float* Wv = (const float*)d_in[13];
    const float* bv = (const float*)d_in[14];
    // d_in[15] Wg, d_in[16] bg: softmax-invariant, skipped.
    const float* pos_key = (const float*)d_in[17];
    const float* Wl = (const float*)d_in[18];
    const float* bl = (const float*)d_in[19];
    const float* W_out = (const float*)d_in[20];
    const float* b_out = (const float*)d_in[21];
    float* out = (float*)d_out;

    const size_t SZ = (size_t)M_ * E_;  // elements per activation buffer
    float* X = (float*)d_ws;
    float* Qb = X + SZ;
    float* Kb = Qb + SZ;
    float* Vb = Kb + SZ;

    const dim3 gg(E_ / 64, M_ / 64);  // (16, 64)
    const dim3 bb(256);

    embed_gemm<<<gg, bb, 0, stream>>>(item_inputs, skill_inputs, emb_item,
                                      emb_skill, W_in, b_in, X);
    for (int l = 0; l < L_; ++l) {
        const float* Wq_l = Wq + (size_t)l * E_ * E_;
        const float* Wk_l = Wk + (size_t)l * E_ * E_;
        const float* Wv_l = Wv + (size_t)l * E_ * E_;
        const float* pe_l = pos_key + (size_t)l * S_ * D_;
        gemm_nt<0, 0><<<gg, bb, 0, stream>>>(X, Wq_l, bq + l * E_, Qb, E_, nullptr);
        gemm_nt<0, 1><<<gg, bb, 0, stream>>>(Qb, Wk_l, bk + l * E_, Kb, E_, pe_l);
        gemm_nt<0, 0><<<gg, bb, 0, stream>>>(Qb, Wv_l, bv + l * E_, Vb, E_, nullptr);
        attn_kernel<<<dim3(S_ / 32, B_ * H_), bb, 0, stream>>>(Qb, Kb, Vb, X);
        gemm_nt<1, 0><<<gg, bb, 0, stream>>>(
            X, Wl + ((size_t)l * 3 + 0) * E_ * E_, bl + (l * 3 + 0) * E_, Qb, E_, nullptr);
        gemm_nt<1, 0><<<gg, bb, 0, stream>>>(
            Qb, Wl + ((size_t)l * 3 + 1) * E_ * E_, bl + (l * 3 + 1) * E_, Kb, E_, nullptr);
        gemm_nt<1, 0><<<gg, bb, 0, stream>>>(
            Kb, Wl + ((size_t)l * 3 + 2) * E_ * E_, bl + (l * 3 + 2) * E_, X, E_, nullptr);
    }
    final_proj<<<dim3(M_ / 4), bb, 0, stream>>>(X, W_out, b_out, out);
}

// Round 3
// 1798.374 us; speedup vs baseline: 2.2457x; 2.2457x over previous
//
#include <hip/hip_runtime.h>
#include <hip/hip_bf16.h>

// AKT forward, round 3: all GEMMs -> bf16 MFMA (16x16x32), attn stays f32-compute.
//   - glo term dropped (softmax-invariant per-query constant)
//   - pos_key folded into k-GEMM epilogue
//   - bf16 activation chain, f32 accumulation + f32 epilogues
//   - GEMM: BM=128,BN=64,BK=32, global_load_lds w=16, XOR-swizzled (both sides)
// Workspace (64 MB): Xc[4096,2048]bf16 | X,Q,K,V [4096,1024]bf16 | W_in bf16 | Wbuf 6x1M bf16

#define B_ 4
#define S_ 1024
#define E_ 1024
#define H_ 16
#define D_ 64
#define L_ 4
#define M_ (B_ * S_)  // 4096
#define EE (E_ * E_)  // 1M

typedef __attribute__((ext_vector_type(8))) __bf16 bf16x8;
typedef __attribute__((ext_vector_type(4))) float f32x4;
typedef __attribute__((ext_vector_type(8))) unsigned short u16x8;

__device__ __forceinline__ float bf2f(unsigned short u) {
    union { unsigned int i; float f; } x;
    x.i = ((unsigned int)u) << 16;
    return x.f;
}
__device__ __forceinline__ float gelu_exact(float x) {
    return 0.5f * x * (1.0f + erff(x * 0.70710678118654752f));
}

// ---------------------------------------------------------------------------
// f32 -> bf16 bulk convert
// ---------------------------------------------------------------------------
__global__ __launch_bounds__(256) void cvt_f32_bf16(
    const float* __restrict__ in, __bf16* __restrict__ out, int n) {
    const int i = (blockIdx.x * 256 + threadIdx.x) * 4;
    if (i >= n) return;
    const float4 v = *(const float4*)(in + i);
    __bf16* o = out + i;
    o[0] = (__bf16)v.x; o[1] = (__bf16)v.y; o[2] = (__bf16)v.z; o[3] = (__bf16)v.w;
}

// per-layer: Wq,Wk,Wv,Wl[0..2] (each 1M f32) -> Wbuf[6M] bf16
__global__ __launch_bounds__(256) void cvt_layer_weights(
    const float* __restrict__ Wq, const float* __restrict__ Wk,
    const float* __restrict__ Wv, const float* __restrict__ Wl,
    __bf16* __restrict__ out) {
    const int i = (blockIdx.x * 256 + threadIdx.x) * 4;  // < 6M
    const int mat = i >> 20;
    const int off = i & (EE - 1);
    const float* src = (mat == 0) ? Wq : (mat == 1) ? Wk : (mat == 2) ? Wv
                                        : Wl + (size_t)(mat - 3) * EE;
    const float4 v = *(const float4*)(src + off);
    __bf16* o = out + i;
    o[0] = (__bf16)v.x; o[1] = (__bf16)v.y; o[2] = (__bf16)v.z; o[3] = (__bf16)v.w;
}

// ---------------------------------------------------------------------------
// Xc[r, 0:2048] = bf16(concat(emb_item[item_idx[r]], emb_skill[skill_idx[r]]))
// ---------------------------------------------------------------------------
__global__ __launch_bounds__(256) void embed_gather(
    const int* __restrict__ item_idx, const int* __restrict__ skill_idx,
    const float* __restrict__ emb_item, const float* __restrict__ emb_skill,
    __bf16* __restrict__ Xc) {
    const int r = blockIdx.x;
    const int c = threadIdx.x * 8;
    const float* s = (c < E_) ? emb_item + (size_t)item_idx[r] * E_ + c
                              : emb_skill + (size_t)skill_idx[r] * E_ + (c - E_);
    const float4 a = *(const float4*)s;
    const float4 b = *(const float4*)(s + 4);
    __bf16* o = Xc + (size_t)r * 2048 + c;
    o[0] = (__bf16)a.x; o[1] = (__bf16)a.y; o[2] = (__bf16)a.z; o[3] = (__bf16)a.w;
    o[4] = (__bf16)b.x; o[5] = (__bf16)b.y; o[6] = (__bf16)b.z; o[7] = (__bf16)b.w;
}

// ---------------------------------------------------------------------------
// C[M_,1024]bf16 = A[M_,K]bf16 * Bm[1024,K]bf16^T + bias(f32); opt GELU / pe.
// BM=128, BN=64, BK=32. 256 threads = 4 waves (2x2), wave tile 64x32.
// global_load_lds(16B) with inverse-swizzled source; swizzled ds_read_b128.
// Swizzle: 16B-chunk col-group cg' = cg ^ (row & 3)  (involution).
// ---------------------------------------------------------------------------
template <int ACT, int ADD_PE>
__global__ __launch_bounds__(256) void gemm_bf16(
    const __bf16* __restrict__ A, const __bf16* __restrict__ Bm,
    const float* __restrict__ bias, __bf16* __restrict__ C, int K,
    const float* __restrict__ pe) {
    __shared__ __bf16 As[128 * 32];
    __shared__ __bf16 Bs[64 * 32];
    const int tid = threadIdx.x;
    const int lane = tid & 63;
    const int wid = tid >> 6;
    const int wm = wid >> 1;  // 0..1 : row block *64
    const int wn = wid & 1;   // 0..1 : col block *32
    const int m0 = blockIdx.y * 128;
    const int n0 = blockIdx.x * 64;

    // staging chunks (16B each). A: 512 chunks (2/thread), B: 256 (1/thread).
    const int ca0 = wid * 128 + lane;
    const int ca1 = ca0 + 64;
    const int cb = wid * 64 + lane;
    const int ra0 = ca0 >> 2, ga0 = (ca0 & 3) ^ (ra0 & 3);
    const int ra1 = ca1 >> 2, ga1 = (ca1 & 3) ^ (ra1 & 3);
    const int rb = cb >> 2, gb = (cb & 3) ^ (rb & 3);
    const __bf16* pa0 = A + (size_t)(m0 + ra0) * K + ga0 * 8;
    const __bf16* pa1 = A + (size_t)(m0 + ra1) * K + ga1 * 8;
    const __bf16* pb = Bm + (size_t)(n0 + rb) * K + gb * 8;
    __bf16* lda0 = As + (size_t)(wid * 128) * 8;
    __bf16* lda1 = As + (size_t)(wid * 128 + 64) * 8;
    __bf16* ldb = Bs + (size_t)(wid * 64) * 8;

    // ds_read element offsets (row*32 + (cg ^ (row&3))*8)
    const int acg = lane >> 4;
    int aoff[4], boff[2];
#pragma unroll
    for (int mi = 0; mi < 4; ++mi) {
        const int row = wm * 64 + mi * 16 + (lane & 15);
        aoff[mi] = row * 32 + ((acg ^ (row & 3)) << 3);
    }
#pragma unroll
    for (int ni = 0; ni < 2; ++ni) {
        const int row = wn * 32 + ni * 16 + (lane & 15);
        boff[ni] = row * 32 + ((acg ^ (row & 3)) << 3);
    }

    f32x4 acc[4][2] = {};

    for (int k0 = 0; k0 < K; k0 += 32) {
        __builtin_amdgcn_global_load_lds(
            (const __attribute__((address_space(1))) unsigned int*)(pa0 + k0),
            (__attribute__((address_space(3))) unsigned int*)lda0, 16, 0, 0);
        __builtin_amdgcn_global_load_lds(
            (const __attribute__((address_space(1))) unsigned int*)(pa1 + k0),
            (__attribute__((address_space(3))) unsigned int*)lda1, 16, 0, 0);
        __builtin_amdgcn_global_load_lds(
            (const __attribute__((address_space(1))) unsigned int*)(pb + k0),
            (__attribute__((address_space(3))) unsigned int*)ldb, 16, 0, 0);
        __syncthreads();
        bf16x8 af[4], bfr[2];
#pragma unroll
        for (int mi = 0; mi < 4; ++mi) af[mi] = *(const bf16x8*)(As + aoff[mi]);
#pragma unroll
        for (int ni = 0; ni < 2; ++ni) bfr[ni] = *(const bf16x8*)(Bs + boff[ni]);
#pragma unroll
        for (int mi = 0; mi < 4; ++mi)
#pragma unroll
            for (int ni = 0; ni < 2; ++ni)
                acc[mi][ni] = __builtin_amdgcn_mfma_f32_16x16x32_bf16(
                    af[mi], bfr[ni], acc[mi][ni], 0, 0, 0);
        __syncthreads();
    }

    const int ccol0 = n0 + wn * 32 + (lane & 15);
    const int crow0 = m0 + wm * 64 + ((lane >> 4) << 2);
#pragma unroll
    for (int mi = 0; mi < 4; ++mi) {
#pragma unroll
        for (int ni = 0; ni < 2; ++ni) {
            const int col = ccol0 + ni * 16;
            const float bsum = bias[col];
#pragma unroll
            for (int r = 0; r < 4; ++r) {
                const int row = crow0 + mi * 16 + r;
                float v = acc[mi][ni][r] + bsum;
                if (ADD_PE) v += pe[((row & (S_ - 1)) << 6) + (col & (D_ - 1))];
                if (ACT) v = gelu_exact(v);
                C[(size_t)row * E_ + col] = (__bf16)v;
            }
        }
    }
}

// ---------------------------------------------------------------------------
// Flash attention per (b,h), f32 compute, bf16 I/O. Q tile 32, KV tile 64.
// ---------------------------------------------------------------------------
__global__ __launch_bounds__(256) void attn_kernel(
    const __bf16* __restrict__ Q, const __bf16* __restrict__ Kf,
    const __bf16* __restrict__ V, __bf16* __restrict__ O) {
    __shared__ float Qt[64][36];  // [d][q]
    __shared__ float Kt[64][68];  // [d][k]
    __shared__ float Vs[64][68];  // [k][d]
    __shared__ float Ps[32][68];  // [q][k]
    const int tid = threadIdx.x;
    const int ty = tid >> 4, tx = tid & 15;
    const int qpos = blockIdx.x * 32;
    const int bb = blockIdx.y >> 4;
    const int hh = blockIdx.y & 15;
    const size_t headoff = (size_t)hh * D_;

    {
        const int r = tid >> 3;  // 0..31
        const int c = tid & 7;   // chunk of 8
        const __bf16* qrow = Q + ((size_t)(bb * S_ + qpos + r)) * E_ + headoff + c * 8;
        const u16x8 q = *(const u16x8*)qrow;
#pragma unroll
        for (int j = 0; j < 8; ++j) Qt[c * 8 + j][r] = bf2f(q[j]);
    }

    float m_i[2] = {-INFINITY, -INFINITY};
    float l_i[2] = {0.f, 0.f};
    float o[2][4] = {};

    const int kr = tid >> 2;  // 0..63
    const int c0 = tid & 3;

    for (int kt = 0; kt < S_ / 64; ++kt) {
        __syncthreads();
        {
            const __bf16* krow = Kf + ((size_t)(bb * S_ + kt * 64 + kr)) * E_ + headoff;
            const __bf16* vrow = V + ((size_t)(bb * S_ + kt * 64 + kr)) * E_ + headoff;
#pragma unroll
            for (int cc = c0; cc < 8; cc += 4) {
                const u16x8 kv = *(const u16x8*)(krow + cc * 8);
                const u16x8 vv = *(const u16x8*)(vrow + cc * 8);
#pragma unroll
                for (int j = 0; j < 8; ++j) {
                    Kt[cc * 8 + j][kr] = bf2f(kv[j]);
                    Vs[kr][cc * 8 + j] = bf2f(vv[j]);
                }
            }
        }
        __syncthreads();
        float sc[2][4] = {};
#pragma unroll 8
        for (int d = 0; d < 64; ++d) {
            const float2 aq = *(const float2*)&Qt[d][ty << 1];
            const float4 bk = *(const float4*)&Kt[d][tx << 2];
            const float b4[4] = {bk.x, bk.y, bk.z, bk.w};
#pragma unroll
            for (int j = 0; j < 4; ++j) {
                sc[0][j] = fmaf(aq.x, b4[j], sc[0][j]);
                sc[1][j] = fmaf(aq.y, b4[j], sc[1][j]);
            }
        }
#pragma unroll
        for (int i = 0; i < 2; ++i) {
#pragma unroll
            for (int j = 0; j < 4; ++j) sc[i][j] *= 0.125f;
            float rmax = fmaxf(fmaxf(sc[i][0], sc[i][1]), fmaxf(sc[i][2], sc[i][3]));
#pragma unroll
            for (int off = 1; off < 16; off <<= 1)
                rmax = fmaxf(rmax, __shfl_xor(rmax, off, 16));
            const float mnew = fmaxf(m_i[i], rmax);
            const float corr = __expf(m_i[i] - mnew);
            float p[4], rsum = 0.f;
#pragma unroll
            for (int j = 0; j < 4; ++j) {
                p[j] = __expf(sc[i][j] - mnew);
                rsum += p[j];
            }
#pragma unroll
            for (int off = 1; off < 16; off <<= 1)
                rsum += __shfl_xor(rsum, off, 16);
            l_i[i] = l_i[i] * corr + rsum;
            m_i[i] = mnew;
#pragma unroll
            for (int j = 0; j < 4; ++j) o[i][j] *= corr;
            Ps[(ty << 1) + i][(tx << 2) + 0] = p[0];
            Ps[(ty << 1) + i][(tx << 2) + 1] = p[1];
            Ps[(ty << 1) + i][(tx << 2) + 2] = p[2];
            Ps[(ty << 1) + i][(tx << 2) + 3] = p[3];
        }
        __syncthreads();
#pragma unroll 8
        for (int j = 0; j < 64; ++j) {
            const float pr0 = Ps[(ty << 1) + 0][j];
            const float pr1 = Ps[(ty << 1) + 1][j];
            const float4 vv = *(const float4*)&Vs[j][tx << 2];
            const float v4[4] = {vv.x, vv.y, vv.z, vv.w};
#pragma unroll
            for (int dj = 0; dj < 4; ++dj) {
                o[0][dj] = fmaf(pr0, v4[dj], o[0][dj]);
                o[1][dj] = fmaf(pr1, v4[dj], o[1][dj]);
            }
        }
    }
#pragma unroll
    for (int i = 0; i < 2; ++i) {
        const float inv_l = 1.f / l_i[i];
        __bf16* orow = O + ((size_t)(bb * S_ + qpos + (ty << 1) + i)) * E_ + headoff + (tx << 2);
        orow[0] = (__bf16)(o[i][0] * inv_l);
        orow[1] = (__bf16)(o[i][1] * inv_l);
        orow[2] = (__bf16)(o[i][2] * inv_l);
        orow[3] = (__bf16)(o[i][3] * inv_l);
    }
}

// ---------------------------------------------------------------------------
// out[m] = bf16 x[m,:] . f32 W_out + b_out -> f32. One wave per row.
// ---------------------------------------------------------------------------
__global__ __launch_bounds__(256) void final_proj(
    const __bf16* __restrict__ X, const float* __restrict__ Wout,
    const float* __restrict__ bout, float* __restrict__ out) {
    const int wid = threadIdx.x >> 6, lane = threadIdx.x & 63;
    const int m = blockIdx.x * 4 + wid;
    const __bf16* xrow = X + (size_t)m * E_;
    float acc = 0.f;
#pragma unroll
    for (int c = 0; c < 2; ++c) {
        const int idx = c * 512 + lane * 8;
        const u16x8 xv = *(const u16x8*)(xrow + idx);
        const float4 w1 = *(const float4*)(Wout + idx);
        const float4 w2 = *(const float4*)(Wout + idx + 4);
        acc += bf2f(xv[0]) * w1.x + bf2f(xv[1]) * w1.y + bf2f(xv[2]) * w1.z +
               bf2f(xv[3]) * w1.w + bf2f(xv[4]) * w2.x + bf2f(xv[5]) * w2.y +
               bf2f(xv[6]) * w2.z + bf2f(xv[7]) * w2.w;
    }
#pragma unroll
    for (int off = 32; off; off >>= 1) acc += __shfl_xor(acc, off, 64);
    if (lane == 0) out[m] = acc + bout[0];
}

extern "C" void kernel_launch(void* const* d_in, const int* in_sizes, int n_in,
                              void* d_out, int out_size, void* d_ws, size_t ws_size,
                              hipStream_t stream) {
    const int* item_inputs = (const int*)d_in[0];
    const int* skill_inputs = (const int*)d_in[1];
    const float* emb_item = (const float*)d_in[5];
    const float* emb_skill = (const float*)d_in[6];
    const float* W_in = (const float*)d_in[7];
    const float* b_in = (const float*)d_in[8];
    const float* Wq = (const float*)d_in[9];
    const float* bq = (const float*)d_in[10];
    const float* Wk = (const float*)d_in[11];
    const float* bk = (const float*)d_in[12];
    const float* Wv = (const float*)d_in[13];
    const float* bv = (const float*)d_in[14];
    // d_in[15] Wg, d_in[16] bg: softmax-invariant, skipped.
    const float* pos_key = (const float*)d_in[17];
    const float* Wl = (const float*)d_in[18];
    const float* bl = (const float*)d_in[19];
    const float* W_out = (const float*)d_in[20];
    const float* b_out = (const float*)d_in[21];
    float* out = (float*)d_out;

    const size_t SZ = (size_t)M_ * E_;  // 4M
    __bf16* Xc = (__bf16*)d_ws;         // 8M elems
    __bf16* X = Xc + (size_t)M_ * 2048;
    __bf16* Qb = X + SZ;
    __bf16* Kb = Qb + SZ;
    __bf16* Vb = Kb + SZ;
    __bf16* Winb = Vb + SZ;             // 2M elems
    __bf16* Wbuf = Winb + 2 * EE;       // 6M elems

    const dim3 gg(E_ / 64, M_ / 128);  // (16, 32)
    const dim3 bb(256);

    embed_gather<<<dim3(M_), bb, 0, stream>>>(item_inputs, skill_inputs,
                                              emb_item, emb_skill, Xc);
    cvt_f32_bf16<<<dim3(2 * EE / 1024), bb, 0, stream>>>(W_in, Winb, 2 * EE);
    gemm_bf16<0, 0><<<gg, bb, 0, stream>>>(Xc, Winb, b_in, X, 2048, nullptr);

    for (int l = 0; l < L_; ++l) {
        cvt_layer_weights<<<dim3(6 * EE / 1024), bb, 0, stream>>>(
            Wq + (size_t)l * EE, Wk + (size_t)l * EE, Wv + (size_t)l * EE,
            Wl + (size_t)l * 3 * EE, Wbuf);
        const float* pe_l = pos_key + (size_t)l * S_ * D_;
        gemm_bf16<0, 0><<<gg, bb, 0, stream>>>(X, Wbuf + 0 * EE, bq + l * E_, Qb, E_, nullptr);
        gemm_bf16<0, 1><<<gg, bb, 0, stream>>>(Qb, Wbuf + 1 * EE, bk + l * E_, Kb, E_, pe_l);
        gemm_bf16<0, 0><<<gg, bb, 0, stream>>>(Qb, Wbuf + 2 * EE, bv + l * E_, Vb, E_, nullptr);
        attn_kernel<<<dim3(S_ / 32, B_ * H_), bb, 0, stream>>>(Qb, Kb, Vb, X);
        gemm_bf16<1, 0><<<gg, bb, 0, stream>>>(X, Wbuf + 3 * EE, bl + (l * 3 + 0) * E_, Qb, E_, nullptr);
        gemm_bf16<1, 0><<<gg, bb, 0, stream>>>(Qb, Wbuf + 4 * EE, bl + (l * 3 + 1) * E_, Kb, E_, nullptr);
        gemm_bf16<1, 0><<<gg, bb, 0, stream>>>(Kb, Wbuf + 5 * EE, bl + (l * 3 + 2) * E_, X, E_, nullptr);
    }
    final_proj<<<dim3(M_ / 4), bb, 0, stream>>>(X, W_out, b_out, out);
}

// Round 5
// 1223.462 us; speedup vs baseline: 3.3010x; 1.4699x over previous
//
#include <hip/hip_runtime.h>
#include <hip/hip_bf16.h>

// AKT forward, round 5: GEMMs bf16 MFMA + MFMA flash attention.
//   - glo term dropped (softmax-invariant per-query constant)
//   - pos_key folded into k-GEMM epilogue
//   - attention: bf16 MFMA 16x16x32, no K/V LDS staging (L2-resident),
//     V pre-transposed to [bh][d][s]; P via per-wave swizzled LDS; no barriers.
// Workspace (64 MB): Xc[4096,2048]bf16 (aliased by Vt after embed) |
//   X,Q,K,V [4096,1024]bf16 | W_in bf16 | Wbuf 6x1M bf16

#define B_ 4
#define S_ 1024
#define E_ 1024
#define H_ 16
#define D_ 64
#define L_ 4
#define M_ (B_ * S_)  // 4096
#define EE (E_ * E_)  // 1M

typedef __attribute__((ext_vector_type(8))) __bf16 bf16x8;
typedef __attribute__((ext_vector_type(4))) float f32x4;
typedef __attribute__((ext_vector_type(8))) unsigned short u16x8;

__device__ __forceinline__ float bf2f(unsigned short u) {
    union { unsigned int i; float f; } x;
    x.i = ((unsigned int)u) << 16;
    return x.f;
}
__device__ __forceinline__ float gelu_exact(float x) {
    return 0.5f * x * (1.0f + erff(x * 0.70710678118654752f));
}

// ---------------------------------------------------------------------------
// f32 -> bf16 bulk convert
// ---------------------------------------------------------------------------
__global__ __launch_bounds__(256) void cvt_f32_bf16(
    const float* __restrict__ in, __bf16* __restrict__ out, int n) {
    const int i = (blockIdx.x * 256 + threadIdx.x) * 4;
    if (i >= n) return;
    const float4 v = *(const float4*)(in + i);
    __bf16* o = out + i;
    o[0] = (__bf16)v.x; o[1] = (__bf16)v.y; o[2] = (__bf16)v.z; o[3] = (__bf16)v.w;
}

// per-layer: Wq,Wk,Wv,Wl[0..2] (each 1M f32) -> Wbuf[6M] bf16
__global__ __launch_bounds__(256) void cvt_layer_weights(
    const float* __restrict__ Wq, const float* __restrict__ Wk,
    const float* __restrict__ Wv, const float* __restrict__ Wl,
    __bf16* __restrict__ out) {
    const int i = (blockIdx.x * 256 + threadIdx.x) * 4;  // < 6M
    const int mat = i >> 20;
    const int off = i & (EE - 1);
    const float* src = (mat == 0) ? Wq : (mat == 1) ? Wk : (mat == 2) ? Wv
                                        : Wl + (size_t)(mat - 3) * EE;
    const float4 v = *(const float4*)(src + off);
    __bf16* o = out + i;
    o[0] = (__bf16)v.x; o[1] = (__bf16)v.y; o[2] = (__bf16)v.z; o[3] = (__bf16)v.w;
}

// ---------------------------------------------------------------------------
// Xc[r, 0:2048] = bf16(concat(emb_item[item_idx[r]], emb_skill[skill_idx[r]]))
// ---------------------------------------------------------------------------
__global__ __launch_bounds__(256) void embed_gather(
    const int* __restrict__ item_idx, const int* __restrict__ skill_idx,
    const float* __restrict__ emb_item, const float* __restrict__ emb_skill,
    __bf16* __restrict__ Xc) {
    const int r = blockIdx.x;
    const int c = threadIdx.x * 8;
    const float* s = (c < E_) ? emb_item + (size_t)item_idx[r] * E_ + c
                              : emb_skill + (size_t)skill_idx[r] * E_ + (c - E_);
    const float4 a = *(const float4*)s;
    const float4 b = *(const float4*)(s + 4);
    __bf16* o = Xc + (size_t)r * 2048 + c;
    o[0] = (__bf16)a.x; o[1] = (__bf16)a.y; o[2] = (__bf16)a.z; o[3] = (__bf16)a.w;
    o[4] = (__bf16)b.x; o[5] = (__bf16)b.y; o[6] = (__bf16)b.z; o[7] = (__bf16)b.w;
}

// ---------------------------------------------------------------------------
// C[M_,1024]bf16 = A[M_,K]bf16 * Bm[1024,K]bf16^T + bias(f32); opt GELU / pe.
// BM=128, BN=64, BK=32. 256 threads = 4 waves (2x2), wave tile 64x32.
// ---------------------------------------------------------------------------
template <int ACT, int ADD_PE>
__global__ __launch_bounds__(256) void gemm_bf16(
    const __bf16* __restrict__ A, const __bf16* __restrict__ Bm,
    const float* __restrict__ bias, __bf16* __restrict__ C, int K,
    const float* __restrict__ pe) {
    __shared__ __bf16 As[128 * 32];
    __shared__ __bf16 Bs[64 * 32];
    const int tid = threadIdx.x;
    const int lane = tid & 63;
    const int wid = tid >> 6;
    const int wm = wid >> 1;
    const int wn = wid & 1;
    const int m0 = blockIdx.y * 128;
    const int n0 = blockIdx.x * 64;

    const int ca0 = wid * 128 + lane;
    const int ca1 = ca0 + 64;
    const int cb = wid * 64 + lane;
    const int ra0 = ca0 >> 2, ga0 = (ca0 & 3) ^ (ra0 & 3);
    const int ra1 = ca1 >> 2, ga1 = (ca1 & 3) ^ (ra1 & 3);
    const int rb = cb >> 2, gb = (cb & 3) ^ (rb & 3);
    const __bf16* pa0 = A + (size_t)(m0 + ra0) * K + ga0 * 8;
    const __bf16* pa1 = A + (size_t)(m0 + ra1) * K + ga1 * 8;
    const __bf16* pb = Bm + (size_t)(n0 + rb) * K + gb * 8;
    __bf16* lda0 = As + (size_t)(wid * 128) * 8;
    __bf16* lda1 = As + (size_t)(wid * 128 + 64) * 8;
    __bf16* ldb = Bs + (size_t)(wid * 64) * 8;

    const int acg = lane >> 4;
    int aoff[4], boff[2];
#pragma unroll
    for (int mi = 0; mi < 4; ++mi) {
        const int row = wm * 64 + mi * 16 + (lane & 15);
        aoff[mi] = row * 32 + ((acg ^ (row & 3)) << 3);
    }
#pragma unroll
    for (int ni = 0; ni < 2; ++ni) {
        const int row = wn * 32 + ni * 16 + (lane & 15);
        boff[ni] = row * 32 + ((acg ^ (row & 3)) << 3);
    }

    f32x4 acc[4][2] = {};

    for (int k0 = 0; k0 < K; k0 += 32) {
        __builtin_amdgcn_global_load_lds(
            (const __attribute__((address_space(1))) unsigned int*)(pa0 + k0),
            (__attribute__((address_space(3))) unsigned int*)lda0, 16, 0, 0);
        __builtin_amdgcn_global_load_lds(
            (const __attribute__((address_space(1))) unsigned int*)(pa1 + k0),
            (__attribute__((address_space(3))) unsigned int*)lda1, 16, 0, 0);
        __builtin_amdgcn_global_load_lds(
            (const __attribute__((address_space(1))) unsigned int*)(pb + k0),
            (__attribute__((address_space(3))) unsigned int*)ldb, 16, 0, 0);
        __syncthreads();
        bf16x8 af[4], bfr[2];
#pragma unroll
        for (int mi = 0; mi < 4; ++mi) af[mi] = *(const bf16x8*)(As + aoff[mi]);
#pragma unroll
        for (int ni = 0; ni < 2; ++ni) bfr[ni] = *(const bf16x8*)(Bs + boff[ni]);
#pragma unroll
        for (int mi = 0; mi < 4; ++mi)
#pragma unroll
            for (int ni = 0; ni < 2; ++ni)
                acc[mi][ni] = __builtin_amdgcn_mfma_f32_16x16x32_bf16(
                    af[mi], bfr[ni], acc[mi][ni], 0, 0, 0);
        __syncthreads();
    }

    const int ccol0 = n0 + wn * 32 + (lane & 15);
    const int crow0 = m0 + wm * 64 + ((lane >> 4) << 2);
#pragma unroll
    for (int mi = 0; mi < 4; ++mi) {
#pragma unroll
        for (int ni = 0; ni < 2; ++ni) {
            const int col = ccol0 + ni * 16;
            const float bsum = bias[col];
#pragma unroll
            for (int r = 0; r < 4; ++r) {
                const int row = crow0 + mi * 16 + r;
                float v = acc[mi][ni][r] + bsum;
                if (ADD_PE) v += pe[((row & (S_ - 1)) << 6) + (col & (D_ - 1))];
                if (ACT) v = gelu_exact(v);
                C[(size_t)row * E_ + col] = (__bf16)v;
            }
        }
    }
}

// ---------------------------------------------------------------------------
// Vt[(bh*64 + d)*1024 + s] = Vb[(b*1024+s)*1024 + h*64 + d]
// grid (16 s-tiles, 64 bh), 64x64 tile through LDS (ushort — bf16 bits opaque).
// ---------------------------------------------------------------------------
__global__ __launch_bounds__(256) void v_transpose(
    const __bf16* __restrict__ Vb, __bf16* __restrict__ Vt) {
    __shared__ unsigned short T[64][72];  // row stride 144B
    const int tid = threadIdx.x;
    const int s0 = blockIdx.x * 64;
    const int bh = blockIdx.y;
    const int b = bh >> 4, h = bh & 15;
    const unsigned short* Vu = (const unsigned short*)Vb;
#pragma unroll
    for (int p = 0; p < 2; ++p) {
        const int sl = p * 32 + (tid >> 3);
        const int dc = (tid & 7) * 8;
        const u16x8 v = *(const u16x8*)(Vu + (size_t)(b * S_ + s0 + sl) * E_ + h * 64 + dc);
#pragma unroll
        for (int j = 0; j < 8; ++j) T[dc + j][sl] = v[j];
    }
    __syncthreads();
    const int d = tid >> 2;
    const int c = (tid & 3) * 16;
    const u16x8 a = *(const u16x8*)&T[d][c];
    const u16x8 bvv = *(const u16x8*)&T[d][c + 8];
    unsigned short* o = (unsigned short*)Vt + (size_t)(bh * 64 + d) * S_ + s0 + c;
    *(u16x8*)o = a;
    *(u16x8*)(o + 8) = bvv;
}

// ---------------------------------------------------------------------------
// MFMA flash attention. Block = 4 independent waves; wave owns 16 q-rows.
// KV tile = 64 keys. K,Vt fragments direct from global (L2-resident).
// P goes C/D-layout -> A-frag layout through per-wave swizzled LDS.
// ---------------------------------------------------------------------------
__global__ __launch_bounds__(256) void attn_mfma(
    const __bf16* __restrict__ Q, const __bf16* __restrict__ Kf,
    const __bf16* __restrict__ Vt, __bf16* __restrict__ O) {
    __shared__ __bf16 Plds[4 * 16 * 64];  // 8 KB, 2 KB per wave
    const int tid = threadIdx.x;
    const int lane = tid & 63;
    const int w = tid >> 6;
    const int l15 = lane & 15, lhi = lane >> 4;
    const int q0 = blockIdx.x * 64 + w * 16;
    const int bb = blockIdx.y >> 4, hh = blockIdx.y & 15;

    // Q fragments, pre-scaled by 1/8 (exact: power of two)
    bf16x8 qf[2];
    {
        const __bf16* qrow =
            Q + (size_t)(bb * S_ + q0 + l15) * E_ + hh * 64 + lhi * 8;
#pragma unroll
        for (int kc = 0; kc < 2; ++kc) {
            const u16x8 raw = *(const u16x8*)(qrow + kc * 32);
            bf16x8 v;
#pragma unroll
            for (int j = 0; j < 8; ++j) v[j] = (__bf16)(bf2f(raw[j]) * 0.125f);
            qf[kc] = v;
        }
    }
    const __bf16* kbase = Kf + (size_t)(bb * S_ + l15) * E_ + hh * 64 + lhi * 8;
    const __bf16* vbase = Vt + (size_t)(blockIdx.y * 64 + l15) * S_ + lhi * 8;
    char* pw = (char*)Plds + w * 2048;

    float m_r[4] = {-1e30f, -1e30f, -1e30f, -1e30f};
    float l_r[4] = {};
    f32x4 oacc[4] = {};

    for (int kt = 0; kt < S_ / 64; ++kt) {
        // K fragments: B[d][key] = K[key][d]
        bf16x8 kfr[4][2];
#pragma unroll
        for (int kb = 0; kb < 4; ++kb)
#pragma unroll
            for (int kc = 0; kc < 2; ++kc)
                kfr[kb][kc] = *(const bf16x8*)(
                    kbase + (size_t)(kt * 64 + kb * 16) * E_ + kc * 32);
        f32x4 s[4] = {};
#pragma unroll
        for (int kb = 0; kb < 4; ++kb)
#pragma unroll
            for (int kc = 0; kc < 2; ++kc)
                s[kb] = __builtin_amdgcn_mfma_f32_16x16x32_bf16(
                    qf[kc], kfr[kb][kc], s[kb], 0, 0, 0);
        // V fragments: B[k][d] = Vt[d][k]
        bf16x8 vf[4][2];
#pragma unroll
        for (int db = 0; db < 4; ++db)
#pragma unroll
            for (int kc = 0; kc < 2; ++kc)
                vf[db][kc] = *(const bf16x8*)(
                    vbase + (size_t)(db * 16) * S_ + kt * 64 + kc * 32);
        // online softmax (in-lane per r; cross-lane over 16 keys)
        float p[4][4];  // [kb][r]
#pragma unroll
        for (int r = 0; r < 4; ++r) {
            float mx = fmaxf(fmaxf(s[0][r], s[1][r]), fmaxf(s[2][r], s[3][r]));
#pragma unroll
            for (int off = 1; off < 16; off <<= 1)
                mx = fmaxf(mx, __shfl_xor(mx, off, 16));
            const float mnew = fmaxf(m_r[r], mx);
            const float corr = __expf(m_r[r] - mnew);
            float rs = 0.f;
#pragma unroll
            for (int kb = 0; kb < 4; ++kb) {
                p[kb][r] = __expf(s[kb][r] - mnew);
                rs += p[kb][r];
            }
#pragma unroll
            for (int off = 1; off < 16; off <<= 1)
                rs += __shfl_xor(rs, off, 16);
            l_r[r] = l_r[r] * corr + rs;
            m_r[r] = mnew;
#pragma unroll
            for (int db = 0; db < 4; ++db) oacc[db][r] *= corr;
        }
        // write P (C/D layout -> swizzled LDS rows)
#pragma unroll
        for (int r = 0; r < 4; ++r) {
            const int q = lhi * 4 + r;
            const int sw = (q & 7) << 4;
#pragma unroll
            for (int kb = 0; kb < 4; ++kb) {
                const int off = q * 128 + (((kb * 32) + l15 * 2) ^ sw);
                *(__bf16*)(pw + off) = (__bf16)p[kb][r];
            }
        }
        // read P as A-fragments
        bf16x8 pf[2];
#pragma unroll
        for (int kc = 0; kc < 2; ++kc) {
            const int off = l15 * 128 + ((kc * 64 + lhi * 16) ^ ((l15 & 7) << 4));
            pf[kc] = *(const bf16x8*)(pw + off);
        }
#pragma unroll
        for (int db = 0; db < 4; ++db)
#pragma unroll
            for (int kc = 0; kc < 2; ++kc)
                oacc[db] = __builtin_amdgcn_mfma_f32_16x16x32_bf16(
                    pf[kc], vf[db][kc], oacc[db], 0, 0, 0);
    }
    // epilogue: O[q][d] = oacc / l
#pragma unroll
    for (int r = 0; r < 4; ++r) {
        const float inv_l = 1.f / l_r[r];
        __bf16* orow =
            O + (size_t)(bb * S_ + q0 + lhi * 4 + r) * E_ + hh * 64 + l15;
#pragma unroll
        for (int db = 0; db < 4; ++db)
            orow[db * 16] = (__bf16)(oacc[db][r] * inv_l);
    }
}

// ---------------------------------------------------------------------------
// out[m] = bf16 x[m,:] . f32 W_out + b_out -> f32. One wave per row.
// ---------------------------------------------------------------------------
__global__ __launch_bounds__(256) void final_proj(
    const __bf16* __restrict__ X, const float* __restrict__ Wout,
    const float* __restrict__ bout, float* __restrict__ out) {
    const int wid = threadIdx.x >> 6, lane = threadIdx.x & 63;
    const int m = blockIdx.x * 4 + wid;
    const __bf16* xrow = X + (size_t)m * E_;
    float acc = 0.f;
#pragma unroll
    for (int c = 0; c < 2; ++c) {
        const int idx = c * 512 + lane * 8;
        const u16x8 xv = *(const u16x8*)(xrow + idx);
        const float4 w1 = *(const float4*)(Wout + idx);
        const float4 w2 = *(const float4*)(Wout + idx + 4);
        acc += bf2f(xv[0]) * w1.x + bf2f(xv[1]) * w1.y + bf2f(xv[2]) * w1.z +
               bf2f(xv[3]) * w1.w + bf2f(xv[4]) * w2.x + bf2f(xv[5]) * w2.y +
               bf2f(xv[6]) * w2.z + bf2f(xv[7]) * w2.w;
    }
#pragma unroll
    for (int off = 32; off; off >>= 1) acc += __shfl_xor(acc, off, 64);
    if (lane == 0) out[m] = acc + bout[0];
}

extern "C" void kernel_launch(void* const* d_in, const int* in_sizes, int n_in,
                              void* d_out, int out_size, void* d_ws, size_t ws_size,
                              hipStream_t stream) {
    const int* item_inputs = (const int*)d_in[0];
    const int* skill_inputs = (const int*)d_in[1];
    const float* emb_item = (const float*)d_in[5];
    const float* emb_skill = (const float*)d_in[6];
    const float* W_in = (const float*)d_in[7];
    const float* b_in = (const float*)d_in[8];
    const float* Wq = (const float*)d_in[9];
    const float* bq = (const float*)d_in[10];
    const float* Wk = (const float*)d_in[11];
    const float* bk = (const float*)d_in[12];
    const float* Wv = (const float*)d_in[13];
    const float* bv = (const float*)d_in[14];
    // d_in[15] Wg, d_in[16] bg: softmax-invariant, skipped.
    const float* pos_key = (const float*)d_in[17];
    const float* Wl = (const float*)d_in[18];
    const float* bl = (const float*)d_in[19];
    const float* W_out = (const float*)d_in[20];
    const float* b_out = (const float*)d_in[21];
    float* out = (float*)d_out;

    const size_t SZ = (size_t)M_ * E_;  // 4M
    __bf16* Xc = (__bf16*)d_ws;         // 8M elems (dead after embed GEMM)
    __bf16* Vtb = Xc;                   // aliased: Vt [64][64][1024] = 4M elems
    __bf16* X = Xc + (size_t)M_ * 2048;
    __bf16* Qb = X + SZ;
    __bf16* Kb = Qb + SZ;
    __bf16* Vb = Kb + SZ;
    __bf16* Winb = Vb + SZ;             // 2M elems
    __bf16* Wbuf = Winb + 2 * EE;       // 6M elems

    const dim3 gg(E_ / 64, M_ / 128);  // (16, 32)
    const dim3 bb(256);

    embed_gather<<<dim3(M_), bb, 0, stream>>>(item_inputs, skill_inputs,
                                              emb_item, emb_skill, Xc);
    cvt_f32_bf16<<<dim3(2 * EE / 1024), bb, 0, stream>>>(W_in, Winb, 2 * EE);
    gemm_bf16<0, 0><<<gg, bb, 0, stream>>>(Xc, Winb, b_in, X, 2048, nullptr);

    for (int l = 0; l < L_; ++l) {
        cvt_layer_weights<<<dim3(6 * EE / 1024), bb, 0, stream>>>(
            Wq + (size_t)l * EE, Wk + (size_t)l * EE, Wv + (size_t)l * EE,
            Wl + (size_t)l * 3 * EE, Wbuf);
        const float* pe_l = pos_key + (size_t)l * S_ * D_;
        gemm_bf16<0, 0><<<gg, bb, 0, stream>>>(X, Wbuf + 0 * EE, bq + l * E_, Qb, E_, nullptr);
        gemm_bf16<0, 1><<<gg, bb, 0, stream>>>(Qb, Wbuf + 1 * EE, bk + l * E_, Kb, E_, pe_l);
        gemm_bf16<0, 0><<<gg, bb, 0, stream>>>(Qb, Wbuf + 2 * EE, bv + l * E_, Vb, E_, nullptr);
        v_transpose<<<dim3(S_ / 64, B_ * H_), bb, 0, stream>>>(Vb, Vtb);
        attn_mfma<<<dim3(S_ / 64, B_ * H_), bb, 0, stream>>>(Qb, Kb, Vtb, X);
        gemm_bf16<1, 0><<<gg, bb, 0, stream>>>(X, Wbuf + 3 * EE, bl + (l * 3 + 0) * E_, Qb, E_, nullptr);
        gemm_bf16<1, 0><<<gg, bb, 0, stream>>>(Qb, Wbuf + 4 * EE, bl + (l * 3 + 1) * E_, Kb, E_, nullptr);
        gemm_bf16<1, 0><<<gg, bb, 0, stream>>>(Kb, Wbuf + 5 * EE, bl + (l * 3 + 2) * E_, X, E_, nullptr);
    }
    final_proj<<<dim3(M_ / 4), bb, 0, stream>>>(X, W_out, b_out, out);
}